// Round 7
// baseline (38.372 us; speedup 1.0000x reference)
//
#include <hip/hip_runtime.h>
#include <math.h>

#define BDIM 4096
#define DDIM 128
#define EPSF 1e-12f
#define TI 128
#define TJc 128
#define NSPLIT 16
#define NSLICE (NSPLIT * 2)                 // 32: one slice per 64-col half
#define ITILES (BDIM / TI)                  // 32
#define JT 6                                // (3*4096/128)/NSPLIT
#define FLT_BIG 3.402823466e+38f
#define MATSZ (BDIM * DDIM)                 // 524288
#define YBUF (TJc * DDIM)                   // 16384 ushorts = 32 KB

typedef __attribute__((ext_vector_type(8))) _Float16 f16x8;
typedef __attribute__((ext_vector_type(16))) float f32x16;

// global (pre-swizzled per-lane addr) -> linear LDS, 16B/lane
__device__ __forceinline__ void gload_lds16(const void* g, void* l) {
    __builtin_amdgcn_global_load_lds(
        (const __attribute__((address_space(1))) unsigned int*)(uintptr_t)g,
        (__attribute__((address_space(3))) unsigned int*)(unsigned int)(uintptr_t)l,
        16, 0, 0);
}

__device__ __forceinline__ unsigned int pack2h(float x, float y) {
    _Float16 hx = (_Float16)x, hy = (_Float16)y;
    unsigned short ux, uy;
    __builtin_memcpy(&ux, &hx, 2);
    __builtin_memcpy(&uy, &hy, 2);
    return (unsigned int)ux | ((unsigned int)uy << 16);
}

// ---------------- Kernel 0: fused fp16 convert + row norms + distance_pos ----
__global__ __launch_bounds__(256) void prep_kernel(
    const float* __restrict__ A, const float* __restrict__ P,
    const float* __restrict__ N, ushort* __restrict__ Xf,
    float* __restrict__ a2, float* __restrict__ p2,
    float* __restrict__ n2, float* __restrict__ dpos) {
    int row = (blockIdx.x * blockDim.x + threadIdx.x) >> 6;
    int lane = threadIdx.x & 63;
    if (row >= BDIM) return;
    const float2 av = *(const float2*)&A[row * DDIM + lane * 2];
    const float2 pv = *(const float2*)&P[row * DDIM + lane * 2];
    const float2 nv = *(const float2*)&N[row * DDIM + lane * 2];
    *(unsigned int*)&Xf[0 * MATSZ + row * DDIM + lane * 2] = pack2h(av.x, av.y);
    *(unsigned int*)&Xf[1 * MATSZ + row * DDIM + lane * 2] = pack2h(pv.x, pv.y);
    *(unsigned int*)&Xf[2 * MATSZ + row * DDIM + lane * 2] = pack2h(nv.x, nv.y);
    float sa = av.x * av.x + av.y * av.y;
    float sp = pv.x * pv.x + pv.y * pv.y;
    float sn = nv.x * nv.x + nv.y * nv.y;
    float dx = av.x - pv.x, dy = av.y - pv.y;
    float sd = dx * dx + dy * dy;
    #pragma unroll
    for (int off = 32; off; off >>= 1) {
        sa += __shfl_down(sa, off);
        sp += __shfl_down(sp, off);
        sn += __shfl_down(sn, off);
        sd += __shfl_down(sd, off);
    }
    if (lane == 0) {
        a2[row] = sa;
        p2[row] = sp;
        n2[row] = sn;
        dpos[row] = sqrtf(fmaxf(sd, EPSF));
    }
}

// ---------------- Kernel 1: fp16 MFMA min of (y2/2 - dot) ----------------
// grid (32 i-tiles, 16 splits), 256 thr = 4 waves. Wave = 64 rows x 64 cols:
// 4 acc chains share each B fragment (ds_read:MFMA = 1:2). A fragments come
// straight from global (L2); Y is double-buffered 2x32KB -> 2 blocks/CU.
__global__ __launch_bounds__(256, 2) void minsq_kernel(
    const ushort* __restrict__ Xf,
    const float* __restrict__ a2, const float* __restrict__ p2,
    const float* __restrict__ n2, float* __restrict__ partial) {
    __shared__ __align__(16) ushort Y[2][YBUF];   // 64 KB

    const int tid = threadIdx.x;
    const int w = tid >> 6;
    const int lane = tid & 63;
    const int rg = w >> 1;    // 64-row group of the 128-row i-tile
    const int ch = w & 1;     // 64-col half of the 128-col j-tile
    const int iTile = blockIdx.x;
    const int split = blockIdx.y;
    const int i0 = iTile * TI;
    const int jt0 = split * JT;
    const int sub = lane >> 4, s = lane & 15;

    // stage first Y tile -> Y[0]
    {
        int m = jt0 >> 5, tc = jt0 & 31;
        const ushort* g = Xf + (size_t)m * MATSZ + (size_t)tc * TJc * DDIM;
        #pragma unroll
        for (int q = 0; q < 8; ++q) {
            int r = w * 32 + q * 4 + sub;
            int sp = s ^ (r & 15);
            gload_lds16(g + (size_t)r * DDIM + sp * 8,
                        &Y[0][(w * 32 + q * 4) * DDIM]);
        }
    }
    // A fragments direct from global (prologue only; L2-resident)
    f16x8 a0[8], a1[8];
    {
        const ushort* r0 = Xf + (size_t)(i0 + rg * 64 + (lane & 31)) * DDIM;
        const ushort* r1 = r0 + 32 * DDIM;
        #pragma unroll
        for (int t = 0; t < 8; ++t) {
            int sl = t * 2 + (lane >> 5);
            a0[t] = *(const f16x8*)(r0 + sl * 8);
            a1[t] = *(const f16x8*)(r1 + sl * 8);
        }
    }
    // y2/2 per tile and col-block
    float y2h0[JT], y2h1[JT];
    #pragma unroll
    for (int t = 0; t < JT; ++t) {
        int jt = jt0 + t, m = jt >> 5, tc = jt & 31;
        const float* y2g = (m == 0) ? a2 : ((m == 1) ? p2 : n2);
        int jb = tc * TJc + ch * 64 + (lane & 31);
        y2h0[t] = 0.5f * y2g[jb];
        y2h1[t] = 0.5f * y2g[jb + 32];
    }

    float minv0[16], minv1[16];
    #pragma unroll
    for (int g = 0; g < 16; ++g) { minv0[g] = FLT_BIG; minv1[g] = FLT_BIG; }

    #pragma unroll
    for (int idx = 0; idx < JT; ++idx) {
        // stage tile idx+1 into the other buffer (in flight across compute)
        if (idx + 1 < JT) {
            int jn = jt0 + idx + 1, m = jn >> 5, tc = jn & 31;
            const ushort* g = Xf + (size_t)m * MATSZ + (size_t)tc * TJc * DDIM;
            #pragma unroll
            for (int q = 0; q < 8; ++q) {
                int r = w * 32 + q * 4 + sub;
                int sp = s ^ (r & 15);
                gload_lds16(g + (size_t)r * DDIM + sp * 8,
                            &Y[(idx + 1) & 1][(w * 32 + q * 4) * DDIM]);
            }
            asm volatile("s_waitcnt vmcnt(8)" ::: "memory");  // tile idx done
        } else {
            asm volatile("s_waitcnt vmcnt(0)" ::: "memory");
        }
        __builtin_amdgcn_sched_barrier(0);
        __builtin_amdgcn_s_barrier();            // all waves' tile idx ready
        __builtin_amdgcn_sched_barrier(0);

        const ushort* buf = &Y[idx & 1][0];
        const int rB0 = ch * 64 + (lane & 31);
        const int rB1 = rB0 + 32;
        f32x16 acc00 = {}, acc01 = {}, acc10 = {}, acc11 = {};
        __builtin_amdgcn_s_setprio(1);
        #pragma unroll
        for (int t = 0; t < 8; ++t) {
            int sl = t * 2 + (lane >> 5);
            f16x8 b0 = *(const f16x8*)&buf[rB0 * DDIM + (sl ^ (rB0 & 15)) * 8];
            f16x8 b1 = *(const f16x8*)&buf[rB1 * DDIM + (sl ^ (rB1 & 15)) * 8];
            acc00 = __builtin_amdgcn_mfma_f32_32x32x16_f16(a0[t], b0, acc00, 0, 0, 0);
            acc10 = __builtin_amdgcn_mfma_f32_32x32x16_f16(a1[t], b0, acc10, 0, 0, 0);
            acc01 = __builtin_amdgcn_mfma_f32_32x32x16_f16(a0[t], b1, acc01, 0, 0, 0);
            acc11 = __builtin_amdgcn_mfma_f32_32x32x16_f16(a1[t], b1, acc11, 0, 0, 0);
        }
        __builtin_amdgcn_s_setprio(0);

        // epilogue: running min of (y2/2 - dot); diag exclusion on A/P mats
        {
            int jt = jt0 + idx, m = jt >> 5, tc = jt & 31;
            float yh0 = y2h0[idx], yh1 = y2h1[idx];
            if (m < 2 && tc == iTile) {
                int jg0 = tc * TJc + ch * 64 + (lane & 31);
                int jg1 = jg0 + 32;
                #pragma unroll
                for (int g = 0; g < 16; ++g) {
                    int rloc = (g & 3) + 8 * (g >> 2) + 4 * (lane >> 5);
                    int ig0 = i0 + rg * 64 + rloc;
                    int ig1 = ig0 + 32;
                    float c;
                    c = yh0 - acc00[g]; if (ig0 == jg0) c = FLT_BIG;
                    minv0[g] = fminf(minv0[g], c);
                    c = yh1 - acc01[g]; if (ig0 == jg1) c = FLT_BIG;
                    minv0[g] = fminf(minv0[g], c);
                    c = yh0 - acc10[g]; if (ig1 == jg0) c = FLT_BIG;
                    minv1[g] = fminf(minv1[g], c);
                    c = yh1 - acc11[g]; if (ig1 == jg1) c = FLT_BIG;
                    minv1[g] = fminf(minv1[g], c);
                }
            } else {
                #pragma unroll
                for (int g = 0; g < 16; ++g) {
                    minv0[g] = fminf(minv0[g], fminf(yh0 - acc00[g], yh1 - acc01[g]));
                    minv1[g] = fminf(minv1[g], fminf(yh0 - acc10[g], yh1 - acc11[g]));
                }
            }
        }
        __builtin_amdgcn_s_barrier();   // all waves done reading buf
    }

    // min over the 32 columns of each col-block (within 32-lane halves)
    #pragma unroll
    for (int off = 1; off < 32; off <<= 1) {
        #pragma unroll
        for (int g = 0; g < 16; ++g) {
            minv0[g] = fminf(minv0[g], __shfl_xor(minv0[g], off));
            minv1[g] = fminf(minv1[g], __shfl_xor(minv1[g], off));
        }
    }
    if ((lane & 31) == 0) {
        int hi = lane >> 5;
        int slice = split * 2 + ch;
        #pragma unroll
        for (int g = 0; g < 16; ++g) {
            int rloc = (g & 3) + 8 * (g >> 2) + 4 * hi;
            int ig = i0 + rg * 64 + rloc;
            partial[(size_t)ig * NSLICE + slice] = minv0[g];
            partial[(size_t)(ig + 32) * NSLICE + slice] = minv1[g];
        }
    }
}

// ---------------- Kernel 2a: per-row loss, 16-block partial sums ------------
__global__ __launch_bounds__(256) void lossA_kernel(
    const float* __restrict__ partial, const float* __restrict__ a2,
    const float* __restrict__ dpos, float* __restrict__ bsum) {
    __shared__ float red[4];
    int i = blockIdx.x * 256 + threadIdx.x;
    const float4* pr = (const float4*)&partial[(size_t)i * NSLICE];
    float mv = FLT_BIG;
    #pragma unroll
    for (int q = 0; q < NSLICE / 4; ++q) {
        float4 v = pr[q];
        mv = fminf(mv, fminf(fminf(v.x, v.y), fminf(v.z, v.w)));
    }
    float h2 = a2[i] + 2.0f * mv;
    float hardest = sqrtf(fmaxf(h2, EPSF));
    float x = dpos[i] - hardest;
    float sum = fmaxf(x, 0.f) + log1pf(expf(-fabsf(x)));
    #pragma unroll
    for (int off = 32; off; off >>= 1) sum += __shfl_down(sum, off);
    if ((threadIdx.x & 63) == 0) red[threadIdx.x >> 6] = sum;
    __syncthreads();
    if (threadIdx.x == 0)
        bsum[blockIdx.x] = red[0] + red[1] + red[2] + red[3];
}

// ---------------- Kernel 2b: final scalar ----------------
__global__ void lossB_kernel(const float* __restrict__ bsum,
                             float* __restrict__ out) {
    float v = (threadIdx.x < 16) ? bsum[threadIdx.x] : 0.f;
    #pragma unroll
    for (int off = 32; off; off >>= 1) v += __shfl_down(v, off);
    if (threadIdx.x == 0) out[0] = v * (1.0f / BDIM);
}

extern "C" void kernel_launch(void* const* d_in, const int* in_sizes, int n_in,
                              void* d_out, int out_size, void* d_ws, size_t ws_size,
                              hipStream_t stream) {
    const float* A = (const float*)d_in[0];
    const float* P = (const float*)d_in[1];
    const float* N = (const float*)d_in[2];

    float* ws = (float*)d_ws;
    float* a2 = ws;                          // 4096
    float* p2 = ws + BDIM;                   // 4096
    float* n2 = ws + 2 * BDIM;               // 4096
    float* dpos = ws + 3 * BDIM;             // 4096
    float* bsum = ws + 4 * BDIM;             // 64 (16 used)
    float* partial = ws + 4 * BDIM + 64;     // BDIM * NSLICE (row-major)
    ushort* Xf = (ushort*)(partial + (size_t)BDIM * NSLICE);  // 3*524288 fp16

    prep_kernel<<<BDIM / 4, 256, 0, stream>>>(A, P, N, Xf, a2, p2, n2, dpos);
    dim3 grid2(ITILES, NSPLIT);
    minsq_kernel<<<grid2, 256, 0, stream>>>(Xf, a2, p2, n2, partial);
    lossA_kernel<<<16, 256, 0, stream>>>(partial, a2, dpos, bsum);
    lossB_kernel<<<1, 64, 0, stream>>>(bsum, (float*)d_out);
}